// Round 12
// baseline (196.639 us; speedup 1.0000x reference)
//
#include <hip/hip_runtime.h>

// MultiHeadAttention fused: B=2, T=2048, D=1024, H=16, DH=64.
// Inputs fp32 (per reference), output fp32. Internally bf16 MFMA, fp32 accum.
// Pipeline (5 launches): [prep: cvt x + transpose W] -> [QKV gemm, z-merged,
//   BK=32 dbuf single-barrier, XCD-swizzled, V^T epilogue] -> [flash attn,
//   static-max, KV-CHUNKED coarse (2-barrier)] -> [combine] -> [out gemm
//   128x128 dbuf, XCD-swizzled, + bias]
//
// R12: KV-chunk split. R16: prefetch-after-barrier2. R17: z-merge + V^T
// epilogue + prep fusion. R18: BK=32. R19 (WIN): dbuf single-barrier GEMMs.
// R20 (REVERTED): attn dbuf. R21 (BEST 188.7): + XCD swizzle.
// R22 (REVERTED): fine chunks — occupancy +2.6pt but Opart WRITE doubled
//   (39.5->73.8MB), attn 50->59us. Coarse (<=8 kv-tiles) is the sweet spot.
// R23: out_gemm 64x128 -> 128x128 tiles (same proven qkv structure: 16 MFMA
//   per 4 GLOAD16 vs 8 MFMA per 3) — double arithmetic intensity, 256 blocks.

typedef unsigned short u16;
typedef __attribute__((ext_vector_type(8))) short short8;   // 8 x bf16 (4 VGPRs)
typedef __attribute__((ext_vector_type(4))) short short4_t; // 4 x bf16 (8 B)
typedef __attribute__((ext_vector_type(4))) float f32x4;    // MFMA C/D frag

#define B_ 2
#define T_ 2048
#define D_ 1024
#define H_ 16
#define DH_ 64
#define M_ (B_ * T_)            // 4096 rows of x
#define SCALE_LOG2E 0.18033688011112042f  // (1/sqrt(64)) * log2(e) — folded into Q
#define NEG_BIG -3.0e4f         // mask sentinel: v_exp_f32(NEG_BIG) == 0

// partial-slot geometry: per (bh) 72 slots (qt 8..15: 2, 16..23: 3, 24..31: 4)
// slot payload: 64x64 fp32 O tile [q][dh] + 64 fp32 l  -> 4160 floats
#define SLOT_F 4160
#define SLOTS_PER_BH 72
#define OPART_BYTES ((size_t)32 * SLOTS_PER_BH * SLOT_F * 4)   // 38,338,560
#define WS_BASE_BYTES ((size_t)24 * 1024 * 1024 * 2)           // 48 MB (u16 pools)

// async global->LDS, 16B per lane; LDS dest = wave-uniform base + lane*16
#define GLOAD16(g, l)                                                     \
  __builtin_amdgcn_global_load_lds(                                       \
      (const __attribute__((address_space(1))) void*)(g),                 \
      (__attribute__((address_space(3))) void*)(l), 16, 0, 0)

__device__ __forceinline__ u16 f2bf(float f) {
  union { float f; unsigned u; } v; v.f = f;
  unsigned r = v.u + 0x7fffu + ((v.u >> 16) & 1u);  // RNE
  return (u16)(r >> 16);
}
__device__ __forceinline__ u16 f2bf_trunc(float f) {  // for P >= 0
  union { float f; unsigned u; } v; v.f = f;
  return (u16)(v.u >> 16);
}
__device__ __forceinline__ float exp2_raw(float x) {  // bare v_exp_f32
  float r;
  asm volatile("v_exp_f32 %0, %1" : "=v"(r) : "v"(x));
  return r;
}

// ---------------------------------------------------------------------------
// Kernel 0: fused prep. blocks 0..2047: cvt x fp32->bf16 (8/thread).
// blocks 2048..3071: transpose+convert W[z] 64x64 tile via LDS.
// ---------------------------------------------------------------------------
__global__ __launch_bounds__(256) void prep(
    const float* __restrict__ x, const float* __restrict__ w0,
    const float* __restrict__ w1, const float* __restrict__ w2,
    const float* __restrict__ w3, u16* __restrict__ xb,
    u16* __restrict__ outT) {
  __shared__ u16 Tl[64][72];
  const int id = blockIdx.x;
  const int tid = threadIdx.x;

  if (id < 2048) {  // ---- cvt x ----
    const int i = (id * 256 + tid) * 8;
    float4 a = *(const float4*)(x + i);
    float4 b = *(const float4*)(x + i + 4);
    short8 o;
    o[0] = (short)f2bf(a.x); o[1] = (short)f2bf(a.y);
    o[2] = (short)f2bf(a.z); o[3] = (short)f2bf(a.w);
    o[4] = (short)f2bf(b.x); o[5] = (short)f2bf(b.y);
    o[6] = (short)f2bf(b.z); o[7] = (short)f2bf(b.w);
    *(short8*)(xb + i) = o;
    return;
  }

  // ---- transpose W ----
  const int id2 = id - 2048;
  const int z = id2 >> 8;
  const int rem = id2 & 255;
  const int r0 = (rem >> 4) * 64, c0 = (rem & 15) * 64;
  const float* src = (z == 0) ? w0 : (z == 1) ? w1 : (z == 2) ? w2 : w3;
  const int rr = tid >> 2, cc = (tid & 3) * 16;

  const float* p = src + (size_t)(r0 + rr) * D_ + c0 + cc;
  float4 f0 = *(const float4*)p;
  float4 f1 = *(const float4*)(p + 4);
  float4 f2 = *(const float4*)(p + 8);
  float4 f3 = *(const float4*)(p + 12);
  Tl[rr][cc + 0] = f2bf(f0.x); Tl[rr][cc + 1] = f2bf(f0.y);
  Tl[rr][cc + 2] = f2bf(f0.z); Tl[rr][cc + 3] = f2bf(f0.w);
  Tl[rr][cc + 4] = f2bf(f1.x); Tl[rr][cc + 5] = f2bf(f1.y);
  Tl[rr][cc + 6] = f2bf(f1.z); Tl[rr][cc + 7] = f2bf(f1.w);
  Tl[rr][cc + 8] = f2bf(f2.x); Tl[rr][cc + 9] = f2bf(f2.y);
  Tl[rr][cc +10] = f2bf(f2.z); Tl[rr][cc +11] = f2bf(f2.w);
  Tl[rr][cc +12] = f2bf(f3.x); Tl[rr][cc +13] = f2bf(f3.y);
  Tl[rr][cc +14] = f2bf(f3.z); Tl[rr][cc +15] = f2bf(f3.w);
  __syncthreads();

  u16* o = outT + (size_t)z * D_ * D_ + (size_t)(c0 + rr) * D_ + r0 + cc;
  short8 x0, x1;
#pragma unroll
  for (int i = 0; i < 8; i++) x0[i] = (short)Tl[cc + i][rr];
#pragma unroll
  for (int i = 0; i < 8; i++) x1[i] = (short)Tl[cc + 8 + i][rr];
  *(short8*)o = x0;
  *(short8*)(o + 8) = x1;
}

// ---------------------------------------------------------------------------
// Kernel 1: QKV projection, z-merged, BK=32, LDS dbuf single-barrier (R19),
// XCD-swizzled grid (R21). Epilogue: z<2 -> qkv[z] [bh][t][dh] (Q scaled);
// z==2 -> V^T [bh][dh][t] written directly.
// ---------------------------------------------------------------------------
__global__ __launch_bounds__(256) void qkv_gemm(
    const u16* __restrict__ x, const u16* __restrict__ wT,
    u16* __restrict__ qkv) {
  __shared__ u16 As[2][128][32];  // 8KB per buffer; unpadded (GLOAD16 layout)
  __shared__ u16 Bs[2][128][32];

  // T1 bijective XCD swizzle: 768 blocks, 768 % 8 == 0
  const int flat = blockIdx.y * 24 + blockIdx.x;
  const int swz  = (flat & 7) * 96 + (flat >> 3);
  const int n0 = (swz % 24) * 128;
  const int m0 = (swz / 24) * 128;
  const int z = n0 >> 10;            // 0=Q, 1=K, 2=V (block-uniform)
  const int tid = threadIdx.x;
  const int lane = tid & 63, w = tid >> 6;
  const int quad = lane >> 4, l16 = lane & 15;
  const int wr = w >> 1, wc = w & 1;

  f32x4 acc[4][4] = {};
  const int grow = w * 16 + (lane >> 2);
  const int gcol = (lane & 3) * 8;
  const u16* gAr = x + (size_t)(m0 + grow) * D_ + gcol;
  const u16* gBr = wT + (size_t)(n0 + grow) * D_ + gcol;
  const int woff = w * 512;          // wave slice (u16) within a buffer

  // prologue: stage k0=0 into buffer 0
  {
    u16* lA = (u16*)As + woff;
    u16* lB = (u16*)Bs + woff;
    GLOAD16(gAr, lA);
    GLOAD16(gAr + (size_t)64 * D_, lA + 2048);
    GLOAD16(gBr, lB);
    GLOAD16(gBr + (size_t)64 * D_, lB + 2048);
  }
  __syncthreads();   // drains vmcnt(0): buffer 0 ready

  int cur = 0;
  for (int k0 = 0; k0 < D_; k0 += 32) {
    // 1) stage NEXT tile into buf^1 — flies under this iter's compute
    if (k0 + 32 < D_) {
      u16* lA = (u16*)As + (cur ^ 1) * 4096 + woff;
      u16* lB = (u16*)Bs + (cur ^ 1) * 4096 + woff;
      const u16* gA = gAr + k0 + 32;
      const u16* gB = gBr + k0 + 32;
      GLOAD16(gA, lA);
      GLOAD16(gA + (size_t)64 * D_, lA + 2048);
      GLOAD16(gB, lB);
      GLOAD16(gB + (size_t)64 * D_, lB + 2048);
    }

    // 2) compute from buf[cur]
    short8 af[4], bf[4];
#pragma unroll
    for (int i = 0; i < 4; i++)
      af[i] = *(const short8*)&As[cur][wr * 64 + i * 16 + l16][quad * 8];
#pragma unroll
    for (int i = 0; i < 4; i++)
      bf[i] = *(const short8*)&Bs[cur][wc * 64 + i * 16 + l16][quad * 8];
    __builtin_amdgcn_s_setprio(1);
#pragma unroll
    for (int i = 0; i < 4; i++)
#pragma unroll
      for (int j = 0; j < 4; j++)
        acc[i][j] = __builtin_amdgcn_mfma_f32_16x16x32_bf16(af[i], bf[j], acc[i][j], 0, 0, 0);
    __builtin_amdgcn_s_setprio(0);

    // 3) single barrier: implicit vmcnt(0)+lgkmcnt(0) drain; staging landed
    __syncthreads();
    cur ^= 1;
  }

  if (z < 2) {
    u16* out = qkv + (size_t)z * M_ * D_;
    const float osc = (z == 0) ? SCALE_LOG2E : 1.0f;  // pre-scale Q only
#pragma unroll
    for (int i = 0; i < 4; i++) {
#pragma unroll
      for (int j = 0; j < 4; j++) {
        const int n = n0 + wc * 64 + j * 16 + l16;
        const int h = (n >> 6) & 15, dh = n & 63;
#pragma unroll
        for (int r = 0; r < 4; r++) {
          const int m = m0 + wr * 64 + i * 16 + quad * 4 + r;
          const int b = m >> 11, t = m & (T_ - 1);
          out[(((size_t)(b * H_ + h)) * T_ + t) * DH_ + dh] = f2bf(acc[i][j][r] * osc);
        }
      }
    }
  } else {
    // V^T: [bh][dh][t], t fast. 4 r-values are 4 consecutive t -> 8B store.
    u16* vt = qkv + (size_t)2 * M_ * D_;
#pragma unroll
    for (int i = 0; i < 4; i++) {
      const int mm = m0 + wr * 64 + i * 16 + quad * 4;  // r=0 row; same b for r 0..3
      const int b = mm >> 11, t = mm & (T_ - 1);
#pragma unroll
      for (int j = 0; j < 4; j++) {
        const int n = n0 + wc * 64 + j * 16 + l16;
        const int h = (n >> 6) & 15, dh = n & 63;
        short4_t pk;
#pragma unroll
        for (int r = 0; r < 4; r++) pk[r] = (short)f2bf(acc[i][j][r]);
        *(short4_t*)(vt + ((size_t)(b * H_ + h) * DH_ + dh) * T_ + t) = pk;
      }
    }
  }
}

// ---------------------------------------------------------------------------
// shared helper: slot base within a bh for split q-tile qt (qt in 8..31)
// ---------------------------------------------------------------------------
__device__ __forceinline__ int slot_base(int qt) {
  return (qt < 16) ? (qt - 8) * 2
       : (qt < 24) ? 16 + (qt - 16) * 3
                   : 40 + (qt - 24) * 4;
}

// ---------------------------------------------------------------------------
// Kernel 2: causal flash attention, static-max softmax, KV-CHUNKED coarse
// (R16 two-barrier structure). grid (80, 32), block 128 (2 waves x 32
// q-rows). LDS 27.6KB.
// ---------------------------------------------------------------------------
__global__ __launch_bounds__(128) void attn_chunk(
    const u16* __restrict__ qg, const u16* __restrict__ kg,
    const u16* __restrict__ vtg, u16* __restrict__ ctx,
    float* __restrict__ Opart) {
  __shared__ u16 Ks[64][72];        // [kv][dh], +8 pad
  __shared__ u16 Vs[64][72];        // [dh][kv], +8 pad (from vT global)
  __shared__ u16 Ps[2][2][16][72];  // [wave][qfrag][q][kv 0..63 + pad]

  const int cid = 79 - blockIdx.x;  // big chunks (high qt) dispatch first
  int qt, c, nc;
  if (cid < 8)       { qt = cid;                    c = 0;               nc = 1; }
  else if (cid < 24) { qt = 8  + ((cid - 8) >> 1);  c = (cid - 8) & 1;   nc = 2; }
  else if (cid < 48) { qt = 16 + (cid - 24) / 3;    c = (cid - 24) % 3;  nc = 3; }
  else               { qt = 24 + ((cid - 48) >> 2); c = (cid - 48) & 3;  nc = 4; }
  const int nt = qt + 1;
  const int kv_lo = (c * nt / nc) * 64;
  const int kv_hi = ((c + 1) * nt / nc) * 64;   // exclusive
  const int q0 = qt * 64;

  const int bh = blockIdx.y;
  const int tid = threadIdx.x;
  const int w = tid >> 6, lane = tid & 63;
  const int quad = lane >> 4, l16 = lane & 15;
  const size_t baseQK = (size_t)bh * T_ * DH_;
  const size_t baseV  = (size_t)bh * DH_ * T_;

  const int qrowA = q0 + w * 32 + l16;
  const int qrowB = qrowA + 16;
  short8 qfA0 = *(const short8*)(qg + baseQK + (size_t)qrowA * DH_ + quad * 8);
  short8 qfA1 = *(const short8*)(qg + baseQK + (size_t)qrowA * DH_ + 32 + quad * 8);
  short8 qfB0 = *(const short8*)(qg + baseQK + (size_t)qrowB * DH_ + quad * 8);
  short8 qfB1 = *(const short8*)(qg + baseQK + (size_t)qrowB * DH_ + 32 + quad * 8);

  f32x4 oaccA[4] = {}, oaccB[4] = {};  // O^T: row dh = cb*16+quad*4+r, col q = l16
  float liA = 0.f, liB = 0.f;

  const int srow = tid >> 1;          // 0..63
  const int scol = (tid & 1) * 32;    // 0 or 32

  const u16* kp = kg + baseQK + (size_t)(kv_lo + srow) * DH_ + scol;
  const u16* vp = vtg + baseV + (size_t)srow * T_ + kv_lo + scol;
  short8 kr0 = *(const short8*)kp;
  short8 kr1 = *(const short8*)(kp + 8);
  short8 kr2 = *(const short8*)(kp + 16);
  short8 kr3 = *(const short8*)(kp + 24);
  short8 vr0 = *(const short8*)vp;
  short8 vr1 = *(const short8*)(vp + 8);
  short8 vr2 = *(const short8*)(vp + 16);
  short8 vr3 = *(const short8*)(vp + 24);

  for (int kv0 = kv_lo; kv0 < kv_hi; kv0 += 64) {
    __syncthreads();                 // barrier1: LDS free; drains prefetch
    *(short8*)&Ks[srow][scol]      = kr0;
    *(short8*)&Ks[srow][scol + 8]  = kr1;
    *(short8*)&Ks[srow][scol + 16] = kr2;
    *(short8*)&Ks[srow][scol + 24] = kr3;
    *(short8*)&Vs[srow][scol]      = vr0;
    *(short8*)&Vs[srow][scol + 8]  = vr1;
    *(short8*)&Vs[srow][scol + 16] = vr2;
    *(short8*)&Vs[srow][scol + 24] = vr3;
    __syncthreads();                 // barrier2: LDS ready

    if (kv0 + 64 < kv_hi) {          // R16: loads fly under the compute phase
      const u16* kn = kg + baseQK + (size_t)(kv0 + 64 + srow) * DH_ + scol;
      const u16* vn = vtg + baseV + (size_t)srow * T_ + kv0 + 64 + scol;
      kr0 = *(const short8*)kn;
      kr1 = *(const short8*)(kn + 8);
      kr2 = *(const short8*)(kn + 16);
      kr3 = *(const short8*)(kn + 24);
      vr0 = *(const short8*)vn;
      vr1 = *(const short8*)(vn + 8);
      vr2 = *(const short8*)(vn + 16);
      vr3 = *(const short8*)(vn + 24);
    }

    short8 kf0[4], kf1[4];
#pragma unroll
    for (int cb = 0; cb < 4; cb++) {
      kf0[cb] = *(const short8*)&Ks[cb * 16 + l16][quad * 8];
      kf1[cb] = *(const short8*)&Ks[cb * 16 + l16][32 + quad * 8];
    }

    f32x4 svA[4], svB[4];
    __builtin_amdgcn_s_setprio(1);
#pragma unroll
    for (int cb = 0; cb < 4; cb++) {
      f32x4 z = {};
      svA[cb] = __builtin_amdgcn_mfma_f32_16x16x32_bf16(kf0[cb], qfA0, z, 0, 0, 0);
      svA[cb] = __builtin_amdgcn_mfma_f32_16x16x32_bf16(kf1[cb], qfA1, svA[cb], 0, 0, 0);
      svB[cb] = __builtin_amdgcn_mfma_f32_16x16x32_bf16(kf0[cb], qfB0, z, 0, 0, 0);
      svB[cb] = __builtin_amdgcn_mfma_f32_16x16x32_bf16(kf1[cb], qfB1, svB[cb], 0, 0, 0);
    }
    __builtin_amdgcn_s_setprio(0);

    float pA[4][4], pB[4][4];
    if (kv0 == q0) {
#pragma unroll
      for (int cb = 0; cb < 4; cb++)
#pragma unroll
        for (int r = 0; r < 4; r++) {
          const int kv = kv0 + cb * 16 + quad * 4 + r;
          pA[cb][r] = exp2_raw((kv <= qrowA) ? svA[cb][r] : NEG_BIG);
          pB[cb][r] = exp2_raw((kv <= qrowB) ? svB[cb][r] : NEG_BIG);
        }
    } else {
#pragma unroll
      for (int cb = 0; cb < 4; cb++)
#pragma unroll
        for (int r = 0; r < 4; r++) {
          pA[cb][r] = exp2_raw(svA[cb][r]);
          pB[cb][r] = exp2_raw(svB[cb][r]);
        }
    }
#pragma unroll
    for (int cb = 0; cb < 4; cb++)
#pragma unroll
      for (int r = 0; r < 4; r++) { liA += pA[cb][r]; liB += pB[cb][r]; }

    short8 vf0[4], vf1[4];
#pragma unroll
    for (int cb = 0; cb < 4; cb++) {
      vf0[cb] = *(const short8*)&Vs[cb * 16 + l16][quad * 8];
      vf1[cb] = *(const short8*)&Vs[cb * 16 + l16][32 + quad * 8];
    }

#pragma unroll
    for (int cb = 0; cb < 4; cb++) {
      short4_t pkA, pkB;
#pragma unroll
      for (int r = 0; r < 4; r++) {
        pkA[r] = (short)f2bf_trunc(pA[cb][r]);
        pkB[r] = (short)f2bf_trunc(pB[cb][r]);
      }
      *(short4_t*)&Ps[w][0][l16][cb * 16 + quad * 4] = pkA;
      *(short4_t*)&Ps[w][1][l16][cb * 16 + quad * 4] = pkB;
    }
    short8 paA0 = *(const short8*)&Ps[w][0][l16][quad * 8];
    short8 paA1 = *(const short8*)&Ps[w][0][l16][32 + quad * 8];
    short8 paB0 = *(const short8*)&Ps[w][1][l16][quad * 8];
    short8 paB1 = *(const short8*)&Ps[w][1][l16][32 + quad * 8];
    __builtin_amdgcn_s_setprio(1);
#pragma unroll
    for (int cb = 0; cb < 4; cb++) {
      oaccA[cb] = __builtin_amdgcn_mfma_f32_16x16x32_bf16(vf0[cb], paA0, oaccA[cb], 0, 0, 0);
      oaccA[cb] = __builtin_amdgcn_mfma_f32_16x16x32_bf16(vf1[cb], paA1, oaccA[cb], 0, 0, 0);
      oaccB[cb] = __builtin_amdgcn_mfma_f32_16x16x32_bf16(vf0[cb], paB0, oaccB[cb], 0, 0, 0);
      oaccB[cb] = __builtin_amdgcn_mfma_f32_16x16x32_bf16(vf1[cb], paB1, oaccB[cb], 0, 0, 0);
    }
    __builtin_amdgcn_s_setprio(0);
  }

  liA += __shfl_xor(liA, 16, 64); liA += __shfl_xor(liA, 32, 64);
  liB += __shfl_xor(liB, 16, 64); liB += __shfl_xor(liB, 32, 64);

  if (nc == 1) {
    const int b = bh >> 4, h = bh & 15;
    const float invA = 1.0f / liA, invB = 1.0f / liB;
    u16* outA = ctx + ((size_t)(b * T_ + qrowA)) * D_ + h * 64 + quad * 4;
    u16* outB = ctx + ((size_t)(b * T_ + qrowB)) * D_ + h * 64 + quad * 4;
#pragma unroll
    for (int cb = 0; cb < 4; cb++) {
      short4_t oA, oB;
#pragma unroll
      for (int r = 0; r < 4; r++) {
        oA[r] = (short)f2bf(oaccA[cb][r] * invA);
        oB[r] = (short)f2bf(oaccB[cb][r] * invB);
      }
      *(short4_t*)(outA + cb * 16) = oA;
      *(short4_t*)(outB + cb * 16) = oB;
    }
  } else {
    float* slot = Opart + ((size_t)bh * SLOTS_PER_BH + slot_base(qt) + c) * SLOT_F;
    float* pA = slot + (size_t)(w * 32 + l16) * 64 + quad * 4;
    float* pB = slot + (size_t)(w * 32 + 16 + l16) * 64 + quad * 4;
#pragma unroll
    for (int cb = 0; cb < 4; cb++) {
      *(f32x4*)(pA + cb * 16) = oaccA[cb];
      *(f32x4*)(pB + cb * 16) = oaccB[cb];
    }
    if (quad == 0) {
      slot[4096 + w * 32 + l16] = liA;
      slot[4096 + w * 32 + 16 + l16] = liB;
    }
  }
}

// ---------------------------------------------------------------------------
// Kernel 3: combine partials for qt >= 8. grid (24, 32), block 256.
// ---------------------------------------------------------------------------
__global__ __launch_bounds__(256) void attn_combine(
    const float* __restrict__ Opart, u16* __restrict__ ctx) {
  __shared__ float ls[64];
  const int qt = blockIdx.x + 8;
  const int bh = blockIdx.y;
  const int nc = 1 + (qt >> 3);     // 2, 3 or 4
  const float* slot0 = Opart + ((size_t)bh * SLOTS_PER_BH + slot_base(qt)) * SLOT_F;
  const int tid = threadIdx.x;

  if (tid < 64) {
    float s = 0.f;
    for (int c = 0; c < nc; c++) s += slot0[(size_t)c * SLOT_F + 4096 + tid];
    ls[tid] = 1.0f / s;
  }
  __syncthreads();

  const int q = tid >> 2, d0 = (tid & 3) * 16;
  const float* p = slot0 + (size_t)q * 64 + d0;
  f32x4 a0 = *(const f32x4*)(p);
  f32x4 a1 = *(const f32x4*)(p + 4);
  f32x4 a2 = *(const f32x4*)(p + 8);
  f32x4 a3 = *(const f32x4*)(p + 12);
  for (int c = 1; c < nc; c++) {
    const float* pc = p + (size_t)c * SLOT_F;
    a0 += *(const f32x4*)(pc);
    a1 += *(const f32x4*)(pc + 4);
    a2 += *(const f32x4*)(pc + 8);
    a3 += *(const f32x4*)(pc + 12);
  }
  const float inv = ls[q];
  short8 o0, o1;
#pragma unroll
  for (int i = 0; i < 4; i++) {
    o0[i]     = (short)f2bf(a0[i] * inv);
    o0[i + 4] = (short)f2bf(a1[i] * inv);
    o1[i]     = (short)f2bf(a2[i] * inv);
    o1[i + 4] = (short)f2bf(a3[i] * inv);
  }
  const int b = bh >> 4, h = bh & 15;
  u16* op = ctx + ((size_t)(b * T_ + qt * 64 + q)) * D_ + h * 64 + d0;
  *(short8*)op = o0;
  *(short8*)(op + 8) = o1;
}

// ---------------------------------------------------------------------------
// Kernel 3-mono: fallback if ws too small (uses same vT layout).
// ---------------------------------------------------------------------------
__global__ __launch_bounds__(128) void attn_mono(
    const u16* __restrict__ qg, const u16* __restrict__ kg,
    const u16* __restrict__ vtg, u16* __restrict__ ctx) {
  __shared__ u16 Ks[64][72];
  __shared__ u16 Vs[64][72];
  __shared__ u16 Ps[2][2][16][72];

  const int qt = gridDim.x - 1 - blockIdx.x;
  const int bh = blockIdx.y;
  const int tid = threadIdx.x;
  const int w = tid >> 6, lane = tid & 63;
  const int quad = lane >> 4, l16 = lane & 15;
  const int q0 = qt * 64;
  const size_t baseQK = (size_t)bh * T_ * DH_;
  const size_t baseV  = (size_t)bh * DH_ * T_;

  const int qrowA = q0 + w * 32 + l16;
  const int qrowB = qrowA + 16;
  short8 qfA0 = *(const short8*)(qg + baseQK + (size_t)qrowA * DH_ + quad * 8);
  short8 qfA1 = *(const short8*)(qg + baseQK + (size_t)qrowA * DH_ + 32 + quad * 8);
  short8 qfB0 = *(const short8*)(qg + baseQK + (size_t)qrowB * DH_ + quad * 8);
  short8 qfB1 = *(const short8*)(qg + baseQK + (size_t)qrowB * DH_ + 32 + quad * 8);

  f32x4 oaccA[4] = {}, oaccB[4] = {};
  float liA = 0.f, liB = 0.f;

  const int srow = tid >> 1;
  const int scol = (tid & 1) * 32;

  const u16* kp = kg + baseQK + (size_t)srow * DH_ + scol;
  const u16* vp = vtg + baseV + (size_t)srow * T_ + scol;
  short8 kr0 = *(const short8*)kp;
  short8 kr1 = *(const short8*)(kp + 8);
  short8 kr2 = *(const short8*)(kp + 16);
  short8 kr3 = *(const short8*)(kp + 24);
  short8 vr0 = *(const short8*)vp;
  short8 vr1 = *(const short8*)(vp + 8);
  short8 vr2 = *(const short8*)(vp + 16);
  short8 vr3 = *(const short8*)(vp + 24);

  for (int kv0 = 0; kv0 <= q0; kv0 += 64) {
    __syncthreads();
    *(short8*)&Ks[srow][scol]      = kr0;
    *(short8*)&Ks[srow][scol + 8]  = kr1;
    *(short8*)&Ks[srow][scol + 16] = kr2;
    *(short8*)&Ks[srow][scol + 24] = kr3;
    *(short8*)&Vs[srow][scol]      = vr0;
    *(short8*)&Vs[srow][scol + 8]  = vr1;
    *(short8*)&Vs[srow][scol + 16] = vr2;
    *(short8*)&Vs[srow][scol + 24] = vr3;
    __syncthreads();
    if (kv0 < q0) {
      const u16* kn = kg + baseQK + (size_t)(kv0 + 64 + srow) * DH_ + scol;
      const u16* vn = vtg + baseV + (size_t)srow * T_ + kv0 + 64 + scol;
      kr0 = *(const short8*)kn;
      kr1 = *(const short8*)(kn + 8);
      kr2 = *(const short8*)(kn + 16);
      kr3 = *(const short8*)(kn + 24);
      vr0 = *(const short8*)vn;
      vr1 = *(const short8*)(vn + 8);
      vr2 = *(const short8*)(vn + 16);
      vr3 = *(const short8*)(vn + 24);
    }

    short8 kf0[4], kf1[4];
#pragma unroll
    for (int cb = 0; cb < 4; cb++) {
      kf0[cb] = *(const short8*)&Ks[cb * 16 + l16][quad * 8];
      kf1[cb] = *(const short8*)&Ks[cb * 16 + l16][32 + quad * 8];
    }

    f32x4 svA[4], svB[4];
#pragma unroll
    for (int cb = 0; cb < 4; cb++) {
      f32x4 z = {};
      svA[cb] = __builtin_amdgcn_mfma_f32_16x16x32_bf16(kf0[cb], qfA0, z, 0, 0, 0);
      svA[cb] = __builtin_amdgcn_mfma_f32_16x16x32_bf16(kf1[cb], qfA1, svA[cb], 0, 0, 0);
      svB[cb] = __builtin_amdgcn_mfma_f32_16x16x32_bf16(kf0[cb], qfB0, z, 0, 0, 0);
      svB[cb] = __builtin_amdgcn_mfma_f32_16x16x32_bf16(kf1[cb], qfB1, svB[cb], 0, 0, 0);
    }

    float pA[4][4], pB[4][4];
    if (kv0 == q0) {
#pragma unroll
      for (int cb = 0; cb < 4; cb++)
#pragma unroll
        for (int r = 0; r < 4; r++) {
          const int kv = kv0 + cb * 16 + quad * 4 + r;
          pA[cb][r] = exp2_raw((kv <= qrowA) ? svA[cb][r] : NEG_BIG);
          pB[cb][r] = exp2_raw((kv <= qrowB) ? svB[cb][r] : NEG_BIG);
        }
    } else {
#pragma unroll
      for (int cb = 0; cb < 4; cb++)
#pragma unroll
        for (int r = 0; r < 4; r++) {
          pA[cb][r] = exp2_raw(svA[cb][r]);
          pB[cb][r] = exp2_raw(svB[cb][r]);
        }
    }
#pragma unroll
    for (int cb = 0; cb < 4; cb++)
#pragma unroll
      for (int r = 0; r < 4; r++) { liA += pA[cb][r]; liB += pB[cb][r]; }

    short8 vf0[4], vf1[4];
#pragma unroll
    for (int cb = 0; cb < 4; cb++) {
      vf0[cb] = *(const short8*)&Vs[cb * 16 + l16][quad * 8];
      vf1[cb] = *(const short8*)&Vs[cb * 16 + l16][32 + quad * 8];
    }

#pragma unroll
    for (int cb = 0; cb < 4; cb++) {
      short4_t pkA, pkB;
#pragma unroll
      for (int r = 0; r < 4; r++) {
        pkA[r] = (short)f2bf_trunc(pA[cb][r]);
        pkB[r] = (short)f2bf_trunc(pB[cb][r]);
      }
      *(short4_t*)&Ps[w][0][l16][cb * 16 + quad * 4] = pkA;
      *(short4_t*)&Ps[w][1][l16][cb * 16 + quad * 4] = pkB;
    }
    short8 paA0 = *(const short8*)&Ps[w][0][l16][quad * 8];
    short8 paA1 = *(const short8*)&Ps[w][0][l16][32 + quad * 8];
    short8 paB0 = *(const short8*)&Ps[w][1][l16][quad * 8];
    short8 paB1 = *(const short8*)&Ps[w][1][l16][32 + quad * 8];
#pragma unroll
    for (int cb = 0; cb < 4; cb++) {
      oaccA[cb] = __builtin_amdgcn_mfma_f32_16x16x32_bf16(vf0[cb], paA0, oaccA[cb], 0, 0, 0);
      oaccA[cb] = __builtin_amdgcn_mfma_f32_16x16x32_bf16(vf1[cb], paA1, oaccA[cb], 0, 0, 0);
      oaccB[cb] = __builtin_amdgcn_mfma_f32_16x16x32_bf16(vf0[cb], paB0, oaccB[cb], 0, 0, 0);
      oaccB[cb] = __builtin_amdgcn_mfma_f32_16x16x32_bf16(vf1[cb], paB1, oaccB[cb], 0, 0, 0);
    }
  }

  liA += __shfl_xor(liA, 16, 64); liA += __shfl_xor(liA, 32, 64);
  liB += __shfl_xor(liB, 16, 64); liB += __shfl_xor(liB, 32, 64);
  const int b = bh >> 4, h = bh & 15;
  const float invA = 1.0f / liA, invB = 1.0f / liB;
  u16* outA = ctx + ((size_t)(b * T_ + qrowA)) * D_ + h * 64 + quad * 4;
  u16* outB = ctx + ((size_t)(b * T_ + qrowB)) * D_ + h * 64 + quad * 4;
#pragma unroll
  for (int cb = 0; cb < 4; cb++) {
    short4_t oA, oB;
#pragma unroll
    for (int r = 0; r < 4; r++) {
      oA[r] = (short)f2bf(oaccA[cb][r] * invA);
      oB[r] = (short)f2bf(oaccB[cb][r] * invB);
    }
    *(short4_t*)(outA + cb * 16) = oA;
    *(short4_t*)(outB + cb * 16) = oB;
  }
}

// ---------------------------------------------------------------------------
// Kernel 4: output projection + bias, 128x128 tile (R23, same structure as
// qkv_gemm: BK=32 dbuf single-barrier, 16 MFMA per 4 GLOAD16), XCD-swizzled.
// out = ctx @ WoT^T + bo. grid 256 blocks, block 256, 4 waves 2x2;
// each wave 64m x 64n (acc[4][4]). fp32 output.
// ---------------------------------------------------------------------------
__global__ __launch_bounds__(256) void out_gemm(
    const u16* __restrict__ ctx, const u16* __restrict__ woT,
    const float* __restrict__ bo, float* __restrict__ out) {
  __shared__ u16 As[2][128][32];
  __shared__ u16 Bs[2][128][32];

  // T1 bijective XCD swizzle: 256 blocks, 256 % 8 == 0
  const int flat = blockIdx.y * 8 + blockIdx.x;
  const int swz  = (flat & 7) * 32 + (flat >> 3);
  const int n0 = (swz % 8) * 128;
  const int m0 = (swz / 8) * 128;
  const int tid = threadIdx.x;
  const int lane = tid & 63, w = tid >> 6;
  const int quad = lane >> 4, l16 = lane & 15;
  const int wr = w >> 1, wc = w & 1;

  f32x4 acc[4][4] = {};
  const int grow = w * 16 + (lane >> 2);
  const int gcol = (lane & 3) * 8;
  const u16* gAr = ctx + (size_t)(m0 + grow) * D_ + gcol;
  const u16* gBr = woT + (size_t)(n0 + grow) * D_ + gcol;
  const int woff = w * 512;

  // prologue: stage k0=0 into buffer 0
  {
    u16* lA = (u16*)As + woff;
    u16* lB = (u16*)Bs + woff;
    GLOAD16(gAr, lA);
    GLOAD16(gAr + (size_t)64 * D_, lA + 2048);
    GLOAD16(gBr, lB);
    GLOAD16(gBr + (size_t)64 * D_, lB + 2048);
  }
  __syncthreads();

  int cur = 0;
  for (int k0 = 0; k0 < D_; k0 += 32) {
    if (k0 + 32 < D_) {
      u16* lA = (u16*)As + (cur ^ 1) * 4096 + woff;
      u16* lB = (u16*)Bs + (cur ^ 1) * 4096 + woff;
      const u16* gA = gAr + k0 + 32;
      const u16* gB = gBr + k0 + 32;
      GLOAD16(gA, lA);
      GLOAD16(gA + (size_t)64 * D_, lA + 2048);
      GLOAD16(gB, lB);
      GLOAD16(gB + (size_t)64 * D_, lB + 2048);
    }

    short8 af[4], bf[4];
#pragma unroll
    for (int i = 0; i < 4; i++)
      af[i] = *(const short8*)&As[cur][wr * 64 + i * 16 + l16][quad * 8];
#pragma unroll
    for (int i = 0; i < 4; i++)
      bf[i] = *(const short8*)&Bs[cur][wc * 64 + i * 16 + l16][quad * 8];
    __builtin_amdgcn_s_setprio(1);
#pragma unroll
    for (int i = 0; i < 4; i++)
#pragma unroll
      for (int j = 0; j < 4; j++)
        acc[i][j] = __builtin_amdgcn_mfma_f32_16x16x32_bf16(af[i], bf[j], acc[i][j], 0, 0, 0);
    __builtin_amdgcn_s_setprio(0);

    __syncthreads();
    cur ^= 1;
  }

#pragma unroll
  for (int i = 0; i < 4; i++) {
#pragma unroll
    for (int j = 0; j < 4; j++) {
      const int n = n0 + wc * 64 + j * 16 + l16;
      const float bias = bo[n];
#pragma unroll
      for (int r = 0; r < 4; r++) {
        const int m = m0 + wr * 64 + i * 16 + quad * 4 + r;
        out[(size_t)m * D_ + n] = acc[i][j][r] + bias;
      }
    }
  }
}

// ---------------------------------------------------------------------------
extern "C" void kernel_launch(void* const* d_in, const int* in_sizes, int n_in,
                              void* d_out, int out_size, void* d_ws, size_t ws_size,
                              hipStream_t stream) {
  const float* x  = (const float*)d_in[0];
  const float* Wq = (const float*)d_in[1];
  const float* Wk = (const float*)d_in[2];
  const float* Wv = (const float*)d_in[3];
  const float* Wo = (const float*)d_in[4];
  const float* bo = (const float*)d_in[5];
  float* out = (float*)d_out;

  // workspace carve (u16 elements): xb[4M] | wT[4M] | qkv[12M] | ctx[4M] = 48MB
  // qkv slot2 holds V^T directly (written by qkv_gemm epilogue).
  // fp32 Opart partial buffer (38.3MB) follows for the chunked-attn path.
  u16* ws  = (u16*)d_ws;
  u16* xb  = ws;                                  // 4096*1024
  u16* wT  = xb + (size_t)M_ * D_;                // 4 * 1024*1024
  u16* qkv = wT + (size_t)4 * D_ * D_;            // Q | K | V^T
  u16* ctx = qkv + (size_t)3 * M_ * D_;           // 4096*1024
  u16* vT  = qkv + (size_t)2 * M_ * D_;
  float* Opart = (float*)(ctx + (size_t)M_ * D_); // at ws + 48MB

  prep<<<dim3(3072), 256, 0, stream>>>(x, Wq, Wk, Wv, Wo, xb, wT);
  qkv_gemm<<<dim3(24, 32), 256, 0, stream>>>(xb, wT, qkv);

  if (ws_size >= WS_BASE_BYTES + OPART_BYTES) {
    attn_chunk<<<dim3(80, B_ * H_), 128, 0, stream>>>(
        qkv, qkv + (size_t)M_ * D_, vT, ctx, Opart);
    attn_combine<<<dim3(24, B_ * H_), 256, 0, stream>>>(Opart, ctx);
  } else {
    attn_mono<<<dim3(T_ / 64, B_ * H_), 128, 0, stream>>>(
        qkv, qkv + (size_t)M_ * D_, vT, ctx);
  }

  out_gemm<<<dim3(8, 32), 256, 0, stream>>>(ctx, wT + (size_t)3 * D_ * D_, bo, out);
}

// Round 14
// 188.294 us; speedup vs baseline: 1.0443x; 1.0443x over previous
//
#include <hip/hip_runtime.h>

// MultiHeadAttention fused: B=2, T=2048, D=1024, H=16, DH=64.
// Inputs fp32 (per reference), output fp32. Internally bf16 MFMA, fp32 accum.
// Pipeline (5 launches): [prep: cvt x + transpose W] -> [QKV gemm, z-merged,
//   BK=32 dbuf single-barrier, XCD-swizzled, V^T epilogue] -> [flash attn,
//   static-max, KV-CHUNKED coarse (2-barrier)] -> [combine] -> [out gemm
//   64x128 dbuf, XCD-swizzled, + bias]
//
// R12: KV-chunk split. R16: prefetch-after-barrier2. R17: z-merge + V^T
// epilogue + prep fusion. R18: BK=32. R19 (WIN): dbuf single-barrier GEMMs.
// R20 (REVERTED): attn dbuf. R21 (BEST 188.7): + XCD swizzle.
// R22 (REVERTED): fine chunks. R23 (REVERTED): 128x128 out_gemm.
// R24: consolidate to exact R21 (best measured config).
// R25: resubmit unchanged (R24 bench was an infra failure, no counters).

typedef unsigned short u16;
typedef __attribute__((ext_vector_type(8))) short short8;   // 8 x bf16 (4 VGPRs)
typedef __attribute__((ext_vector_type(4))) short short4_t; // 4 x bf16 (8 B)
typedef __attribute__((ext_vector_type(4))) float f32x4;    // MFMA C/D frag

#define B_ 2
#define T_ 2048
#define D_ 1024
#define H_ 16
#define DH_ 64
#define M_ (B_ * T_)            // 4096 rows of x
#define SCALE_LOG2E 0.18033688011112042f  // (1/sqrt(64)) * log2(e) — folded into Q
#define NEG_BIG -3.0e4f         // mask sentinel: v_exp_f32(NEG_BIG) == 0

// partial-slot geometry: per (bh) 72 slots (qt 8..15: 2, 16..23: 3, 24..31: 4)
// slot payload: 64x64 fp32 O tile [q][dh] + 64 fp32 l  -> 4160 floats
#define SLOT_F 4160
#define SLOTS_PER_BH 72
#define OPART_BYTES ((size_t)32 * SLOTS_PER_BH * SLOT_F * 4)   // 38,338,560
#define WS_BASE_BYTES ((size_t)24 * 1024 * 1024 * 2)           // 48 MB (u16 pools)

// async global->LDS, 16B per lane; LDS dest = wave-uniform base + lane*16
#define GLOAD16(g, l)                                                     \
  __builtin_amdgcn_global_load_lds(                                       \
      (const __attribute__((address_space(1))) void*)(g),                 \
      (__attribute__((address_space(3))) void*)(l), 16, 0, 0)

__device__ __forceinline__ u16 f2bf(float f) {
  union { float f; unsigned u; } v; v.f = f;
  unsigned r = v.u + 0x7fffu + ((v.u >> 16) & 1u);  // RNE
  return (u16)(r >> 16);
}
__device__ __forceinline__ u16 f2bf_trunc(float f) {  // for P >= 0
  union { float f; unsigned u; } v; v.f = f;
  return (u16)(v.u >> 16);
}
__device__ __forceinline__ float exp2_raw(float x) {  // bare v_exp_f32
  float r;
  asm volatile("v_exp_f32 %0, %1" : "=v"(r) : "v"(x));
  return r;
}

// ---------------------------------------------------------------------------
// Kernel 0: fused prep. blocks 0..2047: cvt x fp32->bf16 (8/thread).
// blocks 2048..3071: transpose+convert W[z] 64x64 tile via LDS.
// ---------------------------------------------------------------------------
__global__ __launch_bounds__(256) void prep(
    const float* __restrict__ x, const float* __restrict__ w0,
    const float* __restrict__ w1, const float* __restrict__ w2,
    const float* __restrict__ w3, u16* __restrict__ xb,
    u16* __restrict__ outT) {
  __shared__ u16 Tl[64][72];
  const int id = blockIdx.x;
  const int tid = threadIdx.x;

  if (id < 2048) {  // ---- cvt x ----
    const int i = (id * 256 + tid) * 8;
    float4 a = *(const float4*)(x + i);
    float4 b = *(const float4*)(x + i + 4);
    short8 o;
    o[0] = (short)f2bf(a.x); o[1] = (short)f2bf(a.y);
    o[2] = (short)f2bf(a.z); o[3] = (short)f2bf(a.w);
    o[4] = (short)f2bf(b.x); o[5] = (short)f2bf(b.y);
    o[6] = (short)f2bf(b.z); o[7] = (short)f2bf(b.w);
    *(short8*)(xb + i) = o;
    return;
  }

  // ---- transpose W ----
  const int id2 = id - 2048;
  const int z = id2 >> 8;
  const int rem = id2 & 255;
  const int r0 = (rem >> 4) * 64, c0 = (rem & 15) * 64;
  const float* src = (z == 0) ? w0 : (z == 1) ? w1 : (z == 2) ? w2 : w3;
  const int rr = tid >> 2, cc = (tid & 3) * 16;

  const float* p = src + (size_t)(r0 + rr) * D_ + c0 + cc;
  float4 f0 = *(const float4*)p;
  float4 f1 = *(const float4*)(p + 4);
  float4 f2 = *(const float4*)(p + 8);
  float4 f3 = *(const float4*)(p + 12);
  Tl[rr][cc + 0] = f2bf(f0.x); Tl[rr][cc + 1] = f2bf(f0.y);
  Tl[rr][cc + 2] = f2bf(f0.z); Tl[rr][cc + 3] = f2bf(f0.w);
  Tl[rr][cc + 4] = f2bf(f1.x); Tl[rr][cc + 5] = f2bf(f1.y);
  Tl[rr][cc + 6] = f2bf(f1.z); Tl[rr][cc + 7] = f2bf(f1.w);
  Tl[rr][cc + 8] = f2bf(f2.x); Tl[rr][cc + 9] = f2bf(f2.y);
  Tl[rr][cc +10] = f2bf(f2.z); Tl[rr][cc +11] = f2bf(f2.w);
  Tl[rr][cc +12] = f2bf(f3.x); Tl[rr][cc +13] = f2bf(f3.y);
  Tl[rr][cc +14] = f2bf(f3.z); Tl[rr][cc +15] = f2bf(f3.w);
  __syncthreads();

  u16* o = outT + (size_t)z * D_ * D_ + (size_t)(c0 + rr) * D_ + r0 + cc;
  short8 x0, x1;
#pragma unroll
  for (int i = 0; i < 8; i++) x0[i] = (short)Tl[cc + i][rr];
#pragma unroll
  for (int i = 0; i < 8; i++) x1[i] = (short)Tl[cc + 8 + i][rr];
  *(short8*)o = x0;
  *(short8*)(o + 8) = x1;
}

// ---------------------------------------------------------------------------
// Kernel 1: QKV projection, z-merged, BK=32, LDS dbuf single-barrier (R19),
// XCD-swizzled grid (R21). Epilogue: z<2 -> qkv[z] [bh][t][dh] (Q scaled);
// z==2 -> V^T [bh][dh][t] written directly.
// ---------------------------------------------------------------------------
__global__ __launch_bounds__(256) void qkv_gemm(
    const u16* __restrict__ x, const u16* __restrict__ wT,
    u16* __restrict__ qkv) {
  __shared__ u16 As[2][128][32];  // 8KB per buffer; unpadded (GLOAD16 layout)
  __shared__ u16 Bs[2][128][32];

  // T1 bijective XCD swizzle: 768 blocks, 768 % 8 == 0
  const int flat = blockIdx.y * 24 + blockIdx.x;
  const int swz  = (flat & 7) * 96 + (flat >> 3);
  const int n0 = (swz % 24) * 128;
  const int m0 = (swz / 24) * 128;
  const int z = n0 >> 10;            // 0=Q, 1=K, 2=V (block-uniform)
  const int tid = threadIdx.x;
  const int lane = tid & 63, w = tid >> 6;
  const int quad = lane >> 4, l16 = lane & 15;
  const int wr = w >> 1, wc = w & 1;

  f32x4 acc[4][4] = {};
  const int grow = w * 16 + (lane >> 2);
  const int gcol = (lane & 3) * 8;
  const u16* gAr = x + (size_t)(m0 + grow) * D_ + gcol;
  const u16* gBr = wT + (size_t)(n0 + grow) * D_ + gcol;
  const int woff = w * 512;          // wave slice (u16) within a buffer

  // prologue: stage k0=0 into buffer 0
  {
    u16* lA = (u16*)As + woff;
    u16* lB = (u16*)Bs + woff;
    GLOAD16(gAr, lA);
    GLOAD16(gAr + (size_t)64 * D_, lA + 2048);
    GLOAD16(gBr, lB);
    GLOAD16(gBr + (size_t)64 * D_, lB + 2048);
  }
  __syncthreads();   // drains vmcnt(0): buffer 0 ready

  int cur = 0;
  for (int k0 = 0; k0 < D_; k0 += 32) {
    // 1) stage NEXT tile into buf^1 — flies under this iter's compute
    if (k0 + 32 < D_) {
      u16* lA = (u16*)As + (cur ^ 1) * 4096 + woff;
      u16* lB = (u16*)Bs + (cur ^ 1) * 4096 + woff;
      const u16* gA = gAr + k0 + 32;
      const u16* gB = gBr + k0 + 32;
      GLOAD16(gA, lA);
      GLOAD16(gA + (size_t)64 * D_, lA + 2048);
      GLOAD16(gB, lB);
      GLOAD16(gB + (size_t)64 * D_, lB + 2048);
    }

    // 2) compute from buf[cur]
    short8 af[4], bf[4];
#pragma unroll
    for (int i = 0; i < 4; i++)
      af[i] = *(const short8*)&As[cur][wr * 64 + i * 16 + l16][quad * 8];
#pragma unroll
    for (int i = 0; i < 4; i++)
      bf[i] = *(const short8*)&Bs[cur][wc * 64 + i * 16 + l16][quad * 8];
    __builtin_amdgcn_s_setprio(1);
#pragma unroll
    for (int i = 0; i < 4; i++)
#pragma unroll
      for (int j = 0; j < 4; j++)
        acc[i][j] = __builtin_amdgcn_mfma_f32_16x16x32_bf16(af[i], bf[j], acc[i][j], 0, 0, 0);
    __builtin_amdgcn_s_setprio(0);

    // 3) single barrier: implicit vmcnt(0)+lgkmcnt(0) drain; staging landed
    __syncthreads();
    cur ^= 1;
  }

  if (z < 2) {
    u16* out = qkv + (size_t)z * M_ * D_;
    const float osc = (z == 0) ? SCALE_LOG2E : 1.0f;  // pre-scale Q only
#pragma unroll
    for (int i = 0; i < 4; i++) {
#pragma unroll
      for (int j = 0; j < 4; j++) {
        const int n = n0 + wc * 64 + j * 16 + l16;
        const int h = (n >> 6) & 15, dh = n & 63;
#pragma unroll
        for (int r = 0; r < 4; r++) {
          const int m = m0 + wr * 64 + i * 16 + quad * 4 + r;
          const int b = m >> 11, t = m & (T_ - 1);
          out[(((size_t)(b * H_ + h)) * T_ + t) * DH_ + dh] = f2bf(acc[i][j][r] * osc);
        }
      }
    }
  } else {
    // V^T: [bh][dh][t], t fast. 4 r-values are 4 consecutive t -> 8B store.
    u16* vt = qkv + (size_t)2 * M_ * D_;
#pragma unroll
    for (int i = 0; i < 4; i++) {
      const int mm = m0 + wr * 64 + i * 16 + quad * 4;  // r=0 row; same b for r 0..3
      const int b = mm >> 11, t = mm & (T_ - 1);
#pragma unroll
      for (int j = 0; j < 4; j++) {
        const int n = n0 + wc * 64 + j * 16 + l16;
        const int h = (n >> 6) & 15, dh = n & 63;
        short4_t pk;
#pragma unroll
        for (int r = 0; r < 4; r++) pk[r] = (short)f2bf(acc[i][j][r]);
        *(short4_t*)(vt + ((size_t)(b * H_ + h) * DH_ + dh) * T_ + t) = pk;
      }
    }
  }
}

// ---------------------------------------------------------------------------
// shared helper: slot base within a bh for split q-tile qt (qt in 8..31)
// ---------------------------------------------------------------------------
__device__ __forceinline__ int slot_base(int qt) {
  return (qt < 16) ? (qt - 8) * 2
       : (qt < 24) ? 16 + (qt - 16) * 3
                   : 40 + (qt - 24) * 4;
}

// ---------------------------------------------------------------------------
// Kernel 2: causal flash attention, static-max softmax, KV-CHUNKED coarse
// (R16 two-barrier structure). grid (80, 32), block 128 (2 waves x 32
// q-rows). LDS 27.6KB.
// ---------------------------------------------------------------------------
__global__ __launch_bounds__(128) void attn_chunk(
    const u16* __restrict__ qg, const u16* __restrict__ kg,
    const u16* __restrict__ vtg, u16* __restrict__ ctx,
    float* __restrict__ Opart) {
  __shared__ u16 Ks[64][72];        // [kv][dh], +8 pad
  __shared__ u16 Vs[64][72];        // [dh][kv], +8 pad (from vT global)
  __shared__ u16 Ps[2][2][16][72];  // [wave][qfrag][q][kv 0..63 + pad]

  const int cid = 79 - blockIdx.x;  // big chunks (high qt) dispatch first
  int qt, c, nc;
  if (cid < 8)       { qt = cid;                    c = 0;               nc = 1; }
  else if (cid < 24) { qt = 8  + ((cid - 8) >> 1);  c = (cid - 8) & 1;   nc = 2; }
  else if (cid < 48) { qt = 16 + (cid - 24) / 3;    c = (cid - 24) % 3;  nc = 3; }
  else               { qt = 24 + ((cid - 48) >> 2); c = (cid - 48) & 3;  nc = 4; }
  const int nt = qt + 1;
  const int kv_lo = (c * nt / nc) * 64;
  const int kv_hi = ((c + 1) * nt / nc) * 64;   // exclusive
  const int q0 = qt * 64;

  const int bh = blockIdx.y;
  const int tid = threadIdx.x;
  const int w = tid >> 6, lane = tid & 63;
  const int quad = lane >> 4, l16 = lane & 15;
  const size_t baseQK = (size_t)bh * T_ * DH_;
  const size_t baseV  = (size_t)bh * DH_ * T_;

  const int qrowA = q0 + w * 32 + l16;
  const int qrowB = qrowA + 16;
  short8 qfA0 = *(const short8*)(qg + baseQK + (size_t)qrowA * DH_ + quad * 8);
  short8 qfA1 = *(const short8*)(qg + baseQK + (size_t)qrowA * DH_ + 32 + quad * 8);
  short8 qfB0 = *(const short8*)(qg + baseQK + (size_t)qrowB * DH_ + quad * 8);
  short8 qfB1 = *(const short8*)(qg + baseQK + (size_t)qrowB * DH_ + 32 + quad * 8);

  f32x4 oaccA[4] = {}, oaccB[4] = {};  // O^T: row dh = cb*16+quad*4+r, col q = l16
  float liA = 0.f, liB = 0.f;

  const int srow = tid >> 1;          // 0..63
  const int scol = (tid & 1) * 32;    // 0 or 32

  const u16* kp = kg + baseQK + (size_t)(kv_lo + srow) * DH_ + scol;
  const u16* vp = vtg + baseV + (size_t)srow * T_ + kv_lo + scol;
  short8 kr0 = *(const short8*)kp;
  short8 kr1 = *(const short8*)(kp + 8);
  short8 kr2 = *(const short8*)(kp + 16);
  short8 kr3 = *(const short8*)(kp + 24);
  short8 vr0 = *(const short8*)vp;
  short8 vr1 = *(const short8*)(vp + 8);
  short8 vr2 = *(const short8*)(vp + 16);
  short8 vr3 = *(const short8*)(vp + 24);

  for (int kv0 = kv_lo; kv0 < kv_hi; kv0 += 64) {
    __syncthreads();                 // barrier1: LDS free; drains prefetch
    *(short8*)&Ks[srow][scol]      = kr0;
    *(short8*)&Ks[srow][scol + 8]  = kr1;
    *(short8*)&Ks[srow][scol + 16] = kr2;
    *(short8*)&Ks[srow][scol + 24] = kr3;
    *(short8*)&Vs[srow][scol]      = vr0;
    *(short8*)&Vs[srow][scol + 8]  = vr1;
    *(short8*)&Vs[srow][scol + 16] = vr2;
    *(short8*)&Vs[srow][scol + 24] = vr3;
    __syncthreads();                 // barrier2: LDS ready

    if (kv0 + 64 < kv_hi) {          // R16: loads fly under the compute phase
      const u16* kn = kg + baseQK + (size_t)(kv0 + 64 + srow) * DH_ + scol;
      const u16* vn = vtg + baseV + (size_t)srow * T_ + kv0 + 64 + scol;
      kr0 = *(const short8*)kn;
      kr1 = *(const short8*)(kn + 8);
      kr2 = *(const short8*)(kn + 16);
      kr3 = *(const short8*)(kn + 24);
      vr0 = *(const short8*)vn;
      vr1 = *(const short8*)(vn + 8);
      vr2 = *(const short8*)(vn + 16);
      vr3 = *(const short8*)(vn + 24);
    }

    short8 kf0[4], kf1[4];
#pragma unroll
    for (int cb = 0; cb < 4; cb++) {
      kf0[cb] = *(const short8*)&Ks[cb * 16 + l16][quad * 8];
      kf1[cb] = *(const short8*)&Ks[cb * 16 + l16][32 + quad * 8];
    }

    f32x4 svA[4], svB[4];
    __builtin_amdgcn_s_setprio(1);
#pragma unroll
    for (int cb = 0; cb < 4; cb++) {
      f32x4 z = {};
      svA[cb] = __builtin_amdgcn_mfma_f32_16x16x32_bf16(kf0[cb], qfA0, z, 0, 0, 0);
      svA[cb] = __builtin_amdgcn_mfma_f32_16x16x32_bf16(kf1[cb], qfA1, svA[cb], 0, 0, 0);
      svB[cb] = __builtin_amdgcn_mfma_f32_16x16x32_bf16(kf0[cb], qfB0, z, 0, 0, 0);
      svB[cb] = __builtin_amdgcn_mfma_f32_16x16x32_bf16(kf1[cb], qfB1, svB[cb], 0, 0, 0);
    }
    __builtin_amdgcn_s_setprio(0);

    float pA[4][4], pB[4][4];
    if (kv0 == q0) {
#pragma unroll
      for (int cb = 0; cb < 4; cb++)
#pragma unroll
        for (int r = 0; r < 4; r++) {
          const int kv = kv0 + cb * 16 + quad * 4 + r;
          pA[cb][r] = exp2_raw((kv <= qrowA) ? svA[cb][r] : NEG_BIG);
          pB[cb][r] = exp2_raw((kv <= qrowB) ? svB[cb][r] : NEG_BIG);
        }
    } else {
#pragma unroll
      for (int cb = 0; cb < 4; cb++)
#pragma unroll
        for (int r = 0; r < 4; r++) {
          pA[cb][r] = exp2_raw(svA[cb][r]);
          pB[cb][r] = exp2_raw(svB[cb][r]);
        }
    }
#pragma unroll
    for (int cb = 0; cb < 4; cb++)
#pragma unroll
      for (int r = 0; r < 4; r++) { liA += pA[cb][r]; liB += pB[cb][r]; }

    short8 vf0[4], vf1[4];
#pragma unroll
    for (int cb = 0; cb < 4; cb++) {
      vf0[cb] = *(const short8*)&Vs[cb * 16 + l16][quad * 8];
      vf1[cb] = *(const short8*)&Vs[cb * 16 + l16][32 + quad * 8];
    }

#pragma unroll
    for (int cb = 0; cb < 4; cb++) {
      short4_t pkA, pkB;
#pragma unroll
      for (int r = 0; r < 4; r++) {
        pkA[r] = (short)f2bf_trunc(pA[cb][r]);
        pkB[r] = (short)f2bf_trunc(pB[cb][r]);
      }
      *(short4_t*)&Ps[w][0][l16][cb * 16 + quad * 4] = pkA;
      *(short4_t*)&Ps[w][1][l16][cb * 16 + quad * 4] = pkB;
    }
    short8 paA0 = *(const short8*)&Ps[w][0][l16][quad * 8];
    short8 paA1 = *(const short8*)&Ps[w][0][l16][32 + quad * 8];
    short8 paB0 = *(const short8*)&Ps[w][1][l16][quad * 8];
    short8 paB1 = *(const short8*)&Ps[w][1][l16][32 + quad * 8];
    __builtin_amdgcn_s_setprio(1);
#pragma unroll
    for (int cb = 0; cb < 4; cb++) {
      oaccA[cb] = __builtin_amdgcn_mfma_f32_16x16x32_bf16(vf0[cb], paA0, oaccA[cb], 0, 0, 0);
      oaccA[cb] = __builtin_amdgcn_mfma_f32_16x16x32_bf16(vf1[cb], paA1, oaccA[cb], 0, 0, 0);
      oaccB[cb] = __builtin_amdgcn_mfma_f32_16x16x32_bf16(vf0[cb], paB0, oaccB[cb], 0, 0, 0);
      oaccB[cb] = __builtin_amdgcn_mfma_f32_16x16x32_bf16(vf1[cb], paB1, oaccB[cb], 0, 0, 0);
    }
    __builtin_amdgcn_s_setprio(0);
  }

  liA += __shfl_xor(liA, 16, 64); liA += __shfl_xor(liA, 32, 64);
  liB += __shfl_xor(liB, 16, 64); liB += __shfl_xor(liB, 32, 64);

  if (nc == 1) {
    const int b = bh >> 4, h = bh & 15;
    const float invA = 1.0f / liA, invB = 1.0f / liB;
    u16* outA = ctx + ((size_t)(b * T_ + qrowA)) * D_ + h * 64 + quad * 4;
    u16* outB = ctx + ((size_t)(b * T_ + qrowB)) * D_ + h * 64 + quad * 4;
#pragma unroll
    for (int cb = 0; cb < 4; cb++) {
      short4_t oA, oB;
#pragma unroll
      for (int r = 0; r < 4; r++) {
        oA[r] = (short)f2bf(oaccA[cb][r] * invA);
        oB[r] = (short)f2bf(oaccB[cb][r] * invB);
      }
      *(short4_t*)(outA + cb * 16) = oA;
      *(short4_t*)(outB + cb * 16) = oB;
    }
  } else {
    float* slot = Opart + ((size_t)bh * SLOTS_PER_BH + slot_base(qt) + c) * SLOT_F;
    float* pA = slot + (size_t)(w * 32 + l16) * 64 + quad * 4;
    float* pB = slot + (size_t)(w * 32 + 16 + l16) * 64 + quad * 4;
#pragma unroll
    for (int cb = 0; cb < 4; cb++) {
      *(f32x4*)(pA + cb * 16) = oaccA[cb];
      *(f32x4*)(pB + cb * 16) = oaccB[cb];
    }
    if (quad == 0) {
      slot[4096 + w * 32 + l16] = liA;
      slot[4096 + w * 32 + 16 + l16] = liB;
    }
  }
}

// ---------------------------------------------------------------------------
// Kernel 3: combine partials for qt >= 8. grid (24, 32), block 256.
// ---------------------------------------------------------------------------
__global__ __launch_bounds__(256) void attn_combine(
    const float* __restrict__ Opart, u16* __restrict__ ctx) {
  __shared__ float ls[64];
  const int qt = blockIdx.x + 8;
  const int bh = blockIdx.y;
  const int nc = 1 + (qt >> 3);     // 2, 3 or 4
  const float* slot0 = Opart + ((size_t)bh * SLOTS_PER_BH + slot_base(qt)) * SLOT_F;
  const int tid = threadIdx.x;

  if (tid < 64) {
    float s = 0.f;
    for (int c = 0; c < nc; c++) s += slot0[(size_t)c * SLOT_F + 4096 + tid];
    ls[tid] = 1.0f / s;
  }
  __syncthreads();

  const int q = tid >> 2, d0 = (tid & 3) * 16;
  const float* p = slot0 + (size_t)q * 64 + d0;
  f32x4 a0 = *(const f32x4*)(p);
  f32x4 a1 = *(const f32x4*)(p + 4);
  f32x4 a2 = *(const f32x4*)(p + 8);
  f32x4 a3 = *(const f32x4*)(p + 12);
  for (int c = 1; c < nc; c++) {
    const float* pc = p + (size_t)c * SLOT_F;
    a0 += *(const f32x4*)(pc);
    a1 += *(const f32x4*)(pc + 4);
    a2 += *(const f32x4*)(pc + 8);
    a3 += *(const f32x4*)(pc + 12);
  }
  const float inv = ls[q];
  short8 o0, o1;
#pragma unroll
  for (int i = 0; i < 4; i++) {
    o0[i]     = (short)f2bf(a0[i] * inv);
    o0[i + 4] = (short)f2bf(a1[i] * inv);
    o1[i]     = (short)f2bf(a2[i] * inv);
    o1[i + 4] = (short)f2bf(a3[i] * inv);
  }
  const int b = bh >> 4, h = bh & 15;
  u16* op = ctx + ((size_t)(b * T_ + qt * 64 + q)) * D_ + h * 64 + d0;
  *(short8*)op = o0;
  *(short8*)(op + 8) = o1;
}

// ---------------------------------------------------------------------------
// Kernel 3-mono: fallback if ws too small (uses same vT layout).
// ---------------------------------------------------------------------------
__global__ __launch_bounds__(128) void attn_mono(
    const u16* __restrict__ qg, const u16* __restrict__ kg,
    const u16* __restrict__ vtg, u16* __restrict__ ctx) {
  __shared__ u16 Ks[64][72];
  __shared__ u16 Vs[64][72];
  __shared__ u16 Ps[2][2][16][72];

  const int qt = gridDim.x - 1 - blockIdx.x;
  const int bh = blockIdx.y;
  const int tid = threadIdx.x;
  const int w = tid >> 6, lane = tid & 63;
  const int quad = lane >> 4, l16 = lane & 15;
  const int q0 = qt * 64;
  const size_t baseQK = (size_t)bh * T_ * DH_;
  const size_t baseV  = (size_t)bh * DH_ * T_;

  const int qrowA = q0 + w * 32 + l16;
  const int qrowB = qrowA + 16;
  short8 qfA0 = *(const short8*)(qg + baseQK + (size_t)qrowA * DH_ + quad * 8);
  short8 qfA1 = *(const short8*)(qg + baseQK + (size_t)qrowA * DH_ + 32 + quad * 8);
  short8 qfB0 = *(const short8*)(qg + baseQK + (size_t)qrowB * DH_ + quad * 8);
  short8 qfB1 = *(const short8*)(qg + baseQK + (size_t)qrowB * DH_ + 32 + quad * 8);

  f32x4 oaccA[4] = {}, oaccB[4] = {};
  float liA = 0.f, liB = 0.f;

  const int srow = tid >> 1;
  const int scol = (tid & 1) * 32;

  const u16* kp = kg + baseQK + (size_t)srow * DH_ + scol;
  const u16* vp = vtg + baseV + (size_t)srow * T_ + scol;
  short8 kr0 = *(const short8*)kp;
  short8 kr1 = *(const short8*)(kp + 8);
  short8 kr2 = *(const short8*)(kp + 16);
  short8 kr3 = *(const short8*)(kp + 24);
  short8 vr0 = *(const short8*)vp;
  short8 vr1 = *(const short8*)(vp + 8);
  short8 vr2 = *(const short8*)(vp + 16);
  short8 vr3 = *(const short8*)(vp + 24);

  for (int kv0 = 0; kv0 <= q0; kv0 += 64) {
    __syncthreads();
    *(short8*)&Ks[srow][scol]      = kr0;
    *(short8*)&Ks[srow][scol + 8]  = kr1;
    *(short8*)&Ks[srow][scol + 16] = kr2;
    *(short8*)&Ks[srow][scol + 24] = kr3;
    *(short8*)&Vs[srow][scol]      = vr0;
    *(short8*)&Vs[srow][scol + 8]  = vr1;
    *(short8*)&Vs[srow][scol + 16] = vr2;
    *(short8*)&Vs[srow][scol + 24] = vr3;
    __syncthreads();
    if (kv0 < q0) {
      const u16* kn = kg + baseQK + (size_t)(kv0 + 64 + srow) * DH_ + scol;
      const u16* vn = vtg + baseV + (size_t)srow * T_ + kv0 + 64 + scol;
      kr0 = *(const short8*)kn;
      kr1 = *(const short8*)(kn + 8);
      kr2 = *(const short8*)(kn + 16);
      kr3 = *(const short8*)(kn + 24);
      vr0 = *(const short8*)vn;
      vr1 = *(const short8*)(vn + 8);
      vr2 = *(const short8*)(vn + 16);
      vr3 = *(const short8*)(vn + 24);
    }

    short8 kf0[4], kf1[4];
#pragma unroll
    for (int cb = 0; cb < 4; cb++) {
      kf0[cb] = *(const short8*)&Ks[cb * 16 + l16][quad * 8];
      kf1[cb] = *(const short8*)&Ks[cb * 16 + l16][32 + quad * 8];
    }

    f32x4 svA[4], svB[4];
#pragma unroll
    for (int cb = 0; cb < 4; cb++) {
      f32x4 z = {};
      svA[cb] = __builtin_amdgcn_mfma_f32_16x16x32_bf16(kf0[cb], qfA0, z, 0, 0, 0);
      svA[cb] = __builtin_amdgcn_mfma_f32_16x16x32_bf16(kf1[cb], qfA1, svA[cb], 0, 0, 0);
      svB[cb] = __builtin_amdgcn_mfma_f32_16x16x32_bf16(kf0[cb], qfB0, z, 0, 0, 0);
      svB[cb] = __builtin_amdgcn_mfma_f32_16x16x32_bf16(kf1[cb], qfB1, svB[cb], 0, 0, 0);
    }

    float pA[4][4], pB[4][4];
    if (kv0 == q0) {
#pragma unroll
      for (int cb = 0; cb < 4; cb++)
#pragma unroll
        for (int r = 0; r < 4; r++) {
          const int kv = kv0 + cb * 16 + quad * 4 + r;
          pA[cb][r] = exp2_raw((kv <= qrowA) ? svA[cb][r] : NEG_BIG);
          pB[cb][r] = exp2_raw((kv <= qrowB) ? svB[cb][r] : NEG_BIG);
        }
    } else {
#pragma unroll
      for (int cb = 0; cb < 4; cb++)
#pragma unroll
        for (int r = 0; r < 4; r++) {
          pA[cb][r] = exp2_raw(svA[cb][r]);
          pB[cb][r] = exp2_raw(svB[cb][r]);
        }
    }
#pragma unroll
    for (int cb = 0; cb < 4; cb++)
#pragma unroll
      for (int r = 0; r < 4; r++) { liA += pA[cb][r]; liB += pB[cb][r]; }

    short8 vf0[4], vf1[4];
#pragma unroll
    for (int cb = 0; cb < 4; cb++) {
      vf0[cb] = *(const short8*)&Vs[cb * 16 + l16][quad * 8];
      vf1[cb] = *(const short8*)&Vs[cb * 16 + l16][32 + quad * 8];
    }

#pragma unroll
    for (int cb = 0; cb < 4; cb++) {
      short4_t pkA, pkB;
#pragma unroll
      for (int r = 0; r < 4; r++) {
        pkA[r] = (short)f2bf_trunc(pA[cb][r]);
        pkB[r] = (short)f2bf_trunc(pB[cb][r]);
      }
      *(short4_t*)&Ps[w][0][l16][cb * 16 + quad * 4] = pkA;
      *(short4_t*)&Ps[w][1][l16][cb * 16 + quad * 4] = pkB;
    }
    short8 paA0 = *(const short8*)&Ps[w][0][l16][quad * 8];
    short8 paA1 = *(const short8*)&Ps[w][0][l16][32 + quad * 8];
    short8 paB0 = *(const short8*)&Ps[w][1][l16][quad * 8];
    short8 paB1 = *(const short8*)&Ps[w][1][l16][32 + quad * 8];
#pragma unroll
    for (int cb = 0; cb < 4; cb++) {
      oaccA[cb] = __builtin_amdgcn_mfma_f32_16x16x32_bf16(vf0[cb], paA0, oaccA[cb], 0, 0, 0);
      oaccA[cb] = __builtin_amdgcn_mfma_f32_16x16x32_bf16(vf1[cb], paA1, oaccA[cb], 0, 0, 0);
      oaccB[cb] = __builtin_amdgcn_mfma_f32_16x16x32_bf16(vf0[cb], paB0, oaccB[cb], 0, 0, 0);
      oaccB[cb] = __builtin_amdgcn_mfma_f32_16x16x32_bf16(vf1[cb], paB1, oaccB[cb], 0, 0, 0);
    }
  }

  liA += __shfl_xor(liA, 16, 64); liA += __shfl_xor(liA, 32, 64);
  liB += __shfl_xor(liB, 16, 64); liB += __shfl_xor(liB, 32, 64);
  const int b = bh >> 4, h = bh & 15;
  const float invA = 1.0f / liA, invB = 1.0f / liB;
  u16* outA = ctx + ((size_t)(b * T_ + qrowA)) * D_ + h * 64 + quad * 4;
  u16* outB = ctx + ((size_t)(b * T_ + qrowB)) * D_ + h * 64 + quad * 4;
#pragma unroll
  for (int cb = 0; cb < 4; cb++) {
    short4_t oA, oB;
#pragma unroll
    for (int r = 0; r < 4; r++) {
      oA[r] = (short)f2bf(oaccA[cb][r] * invA);
      oB[r] = (short)f2bf(oaccB[cb][r] * invB);
    }
    *(short4_t*)(outA + cb * 16) = oA;
    *(short4_t*)(outB + cb * 16) = oB;
  }
}

// ---------------------------------------------------------------------------
// Kernel 4: output projection + bias, BK=32 dbuf single-barrier (R19),
// XCD-swizzled grid (R21). out = ctx @ WoT^T + bo. 64x128 tile -> 512
// blocks, block 256, 4 waves 2x2; each wave 32m x 64n. fp32 output.
// ---------------------------------------------------------------------------
__global__ __launch_bounds__(256) void out_gemm(
    const u16* __restrict__ ctx, const u16* __restrict__ woT,
    const float* __restrict__ bo, float* __restrict__ out) {
  __shared__ u16 As[2][64][32];    // 4KB per buffer
  __shared__ u16 Bs[2][128][32];   // 8KB per buffer

  // T1 bijective XCD swizzle: 512 blocks, 512 % 8 == 0
  const int flat = blockIdx.y * 8 + blockIdx.x;
  const int swz  = (flat & 7) * 64 + (flat >> 3);
  const int n0 = (swz % 8) * 128;
  const int m0 = (swz / 8) * 64;
  const int tid = threadIdx.x;
  const int lane = tid & 63, w = tid >> 6;
  const int quad = lane >> 4, l16 = lane & 15;
  const int wr = w >> 1, wc = w & 1;

  f32x4 acc[2][4] = {};
  const int grow = w * 16 + (lane >> 2);
  const int gcol = (lane & 3) * 8;
  const u16* gAr = ctx + (size_t)(m0 + grow) * D_ + gcol;
  const u16* gBr = woT + (size_t)(n0 + grow) * D_ + gcol;
  const int woff = w * 512;

  // prologue: stage k0=0 into buffer 0
  {
    u16* lA = (u16*)As + woff;     // A buffer = 2048 u16; 4 waves cover it
    u16* lB = (u16*)Bs + woff;
    GLOAD16(gAr, lA);
    GLOAD16(gBr, lB);
    GLOAD16(gBr + (size_t)64 * D_, lB + 2048);
  }
  __syncthreads();

  int cur = 0;
  for (int k0 = 0; k0 < D_; k0 += 32) {
    if (k0 + 32 < D_) {
      u16* lA = (u16*)As + (cur ^ 1) * 2048 + woff;
      u16* lB = (u16*)Bs + (cur ^ 1) * 4096 + woff;
      const u16* gA = gAr + k0 + 32;
      const u16* gB = gBr + k0 + 32;
      GLOAD16(gA, lA);
      GLOAD16(gB, lB);
      GLOAD16(gB + (size_t)64 * D_, lB + 2048);
    }

    short8 af[2], bf[4];
#pragma unroll
    for (int i = 0; i < 2; i++)
      af[i] = *(const short8*)&As[cur][wr * 32 + i * 16 + l16][quad * 8];
#pragma unroll
    for (int i = 0; i < 4; i++)
      bf[i] = *(const short8*)&Bs[cur][wc * 64 + i * 16 + l16][quad * 8];
    __builtin_amdgcn_s_setprio(1);
#pragma unroll
    for (int i = 0; i < 2; i++)
#pragma unroll
      for (int j = 0; j < 4; j++)
        acc[i][j] = __builtin_amdgcn_mfma_f32_16x16x32_bf16(af[i], bf[j], acc[i][j], 0, 0, 0);
    __builtin_amdgcn_s_setprio(0);

    __syncthreads();
    cur ^= 1;
  }

#pragma unroll
  for (int i = 0; i < 2; i++) {
#pragma unroll
    for (int j = 0; j < 4; j++) {
      const int n = n0 + wc * 64 + j * 16 + l16;
      const float bias = bo[n];
#pragma unroll
      for (int r = 0; r < 4; r++) {
        const int m = m0 + wr * 32 + i * 16 + quad * 4 + r;
        out[(size_t)m * D_ + n] = acc[i][j][r] + bias;
      }
    }
  }
}

// ---------------------------------------------------------------------------
extern "C" void kernel_launch(void* const* d_in, const int* in_sizes, int n_in,
                              void* d_out, int out_size, void* d_ws, size_t ws_size,
                              hipStream_t stream) {
  const float* x  = (const float*)d_in[0];
  const float* Wq = (const float*)d_in[1];
  const float* Wk = (const float*)d_in[2];
  const float* Wv = (const float*)d_in[3];
  const float* Wo = (const float*)d_in[4];
  const float* bo = (const float*)d_in[5];
  float* out = (float*)d_out;

  // workspace carve (u16 elements): xb[4M] | wT[4M] | qkv[12M] | ctx[4M] = 48MB
  // qkv slot2 holds V^T directly (written by qkv_gemm epilogue).
  // fp32 Opart partial buffer (38.3MB) follows for the chunked-attn path.
  u16* ws  = (u16*)d_ws;
  u16* xb  = ws;                                  // 4096*1024
  u16* wT  = xb + (size_t)M_ * D_;                // 4 * 1024*1024
  u16* qkv = wT + (size_t)4 * D_ * D_;            // Q | K | V^T
  u16* ctx = qkv + (size_t)3 * M_ * D_;           // 4096*1024
  u16* vT  = qkv + (size_t)2 * M_ * D_;
  float* Opart = (float*)(ctx + (size_t)M_ * D_); // at ws + 48MB

  prep<<<dim3(3072), 256, 0, stream>>>(x, Wq, Wk, Wv, Wo, xb, wT);
  qkv_gemm<<<dim3(24, 32), 256, 0, stream>>>(xb, wT, qkv);

  if (ws_size >= WS_BASE_BYTES + OPART_BYTES) {
    attn_chunk<<<dim3(80, B_ * H_), 128, 0, stream>>>(
        qkv, qkv + (size_t)M_ * D_, vT, ctx, Opart);
    attn_combine<<<dim3(24, B_ * H_), 256, 0, stream>>>(Opart, ctx);
  } else {
    attn_mono<<<dim3(T_ / 64, B_ * H_), 128, 0, stream>>>(
        qkv, qkv + (size_t)M_ * D_, vT, ctx);
  }

  out_gemm<<<dim3(8, 64), 256, 0, stream>>>(ctx, wT + (size_t)3 * D_ * D_, bo, out);
}